// Round 1
// baseline (519.774 us; speedup 1.0000x reference)
//
#include <hip/hip_runtime.h>
#include <hip/hip_bf16.h>

typedef _Float16 f16;
typedef _Float16 f16x8 __attribute__((ext_vector_type(8)));
typedef _Float16 f16x4 __attribute__((ext_vector_type(4)));
typedef float f32x4 __attribute__((ext_vector_type(4)));

#define NBATCH 32
#define WH     1024
#define LSEQ   512
#define DIM    768

// ---------------- cast fp32 -> fp16 (weights) ----------------
__global__ void cast_f32_f16(const float* __restrict__ src, f16* __restrict__ dst, int n) {
    int i = (blockIdx.x * blockDim.x + threadIdx.x) * 4;
    if (i < n) {
        float4 v = *(const float4*)(src + i);
        f16x4 o = { (f16)v.x, (f16)v.y, (f16)v.z, (f16)v.w };
        *(f16x4*)(dst + i) = o;
    }
}

// ---------------- generic batched K-major GEMM ----------------
// C[M,N] = (A[M,K] * B[N,K]^T + bias) * scale   (per batch; B shared if sB==0)
// A is fp32 (converted on stage) or fp16; C fp16 (opt transposed) or fp32.
template<bool A_F32, bool TRANS_OUT, bool OUT_F16, bool HAS_BIAS>
__global__ __launch_bounds__(256, 2) void gemm_k(
    const void* __restrict__ Ap, const f16* __restrict__ Bp,
    const float* __restrict__ bias, float scale,
    void* __restrict__ Cp,
    int M, int N, int K,
    long sA, long sB, long sC)
{
    __shared__ __align__(16) f16 As[128][40];
    __shared__ __align__(16) f16 Bs[128][40];

    const int b  = blockIdx.z;
    const int m0 = blockIdx.x * 128;
    const int n0 = blockIdx.y * 128;
    const int tid  = threadIdx.x;
    const int lane = tid & 63;
    const int w    = tid >> 6;
    const int lo = lane & 15, hi = lane >> 4;
    const int wr = (w >> 1) * 64, wc = (w & 1) * 64;

    const float* Af = (const float*)Ap + (long)b * sA;
    const f16*   Ah = (const f16*)Ap + (long)b * sA;
    const f16*   Bh = Bp + (long)b * sB;

    f32x4 acc[4][4] = {};

    const int sr = tid >> 2;        // 0..63
    const int sk = (tid & 3) * 8;   // 0,8,16,24

    for (int k0 = 0; k0 < K; k0 += 32) {
        __syncthreads();
        #pragma unroll
        for (int it = 0; it < 2; ++it) {
            int row = sr + it * 64;
            if constexpr (A_F32) {
                const float* p = Af + (long)(m0 + row) * K + k0 + sk;
                float4 v0 = *(const float4*)p;
                float4 v1 = *(const float4*)(p + 4);
                f16x8 h = { (f16)v0.x,(f16)v0.y,(f16)v0.z,(f16)v0.w,
                            (f16)v1.x,(f16)v1.y,(f16)v1.z,(f16)v1.w };
                *(f16x8*)&As[row][sk] = h;
            } else {
                *(f16x8*)&As[row][sk] = *(const f16x8*)(Ah + (long)(m0 + row) * K + k0 + sk);
            }
            *(f16x8*)&Bs[row][sk] = *(const f16x8*)(Bh + (long)(n0 + row) * K + k0 + sk);
        }
        __syncthreads();

        f16x8 af[4], bf[4];
        #pragma unroll
        for (int t = 0; t < 4; ++t) {
            af[t] = *(const f16x8*)&As[wr + t*16 + lo][hi*8];
            bf[t] = *(const f16x8*)&Bs[wc + t*16 + lo][hi*8];
        }
        #pragma unroll
        for (int mt = 0; mt < 4; ++mt)
            #pragma unroll
            for (int nt = 0; nt < 4; ++nt)
                acc[mt][nt] = __builtin_amdgcn_mfma_f32_16x16x32_f16(af[mt], bf[nt], acc[mt][nt], 0, 0, 0);
    }

    #pragma unroll
    for (int nt = 0; nt < 4; ++nt) {
        int n = n0 + wc + nt*16 + lo;
        float bv = HAS_BIAS ? bias[n] : 0.0f;
        #pragma unroll
        for (int mt = 0; mt < 4; ++mt) {
            int mbase = m0 + wr + mt*16 + hi*4;
            if constexpr (TRANS_OUT) {
                f16x4 o;
                #pragma unroll
                for (int r = 0; r < 4; ++r) o[r] = (f16)((acc[mt][nt][r] + bv) * scale);
                *(f16x4*)((f16*)Cp + (long)b*sC + (long)n*M + mbase) = o;
            } else if constexpr (OUT_F16) {
                #pragma unroll
                for (int r = 0; r < 4; ++r)
                    ((f16*)Cp)[(long)b*sC + (long)(mbase + r)*N + n] = (f16)((acc[mt][nt][r] + bv) * scale);
            } else {
                #pragma unroll
                for (int r = 0; r < 4; ++r)
                    ((float*)Cp)[(long)b*sC + (long)(mbase + r)*N + n] = (acc[mt][nt][r] + bv) * scale;
            }
        }
    }
}

// ---------------- S = Qp*Kp^T (scaled already), softmax, P fp16 ----------------
// One block = 64 q-rows of one batch; wave w owns 16 q-rows.
// Swapped mfma(K,Q): lane holds S[l = lt*16+hi*4+r][n = lo] -> full row slice per lane.
__global__ __launch_bounds__(256, 2) void attn_s(
    const f16* __restrict__ Qp, const f16* __restrict__ Kp, f16* __restrict__ P)
{
    __shared__ __align__(16) f16 Ks[512][40];
    __shared__ __align__(16) f16 Qs[64][40];

    int bid = blockIdx.x;
    int swz = (bid & 7) * 64 + (bid >> 3);   // 512 blocks, 8 XCDs: 4 batches per XCD
    int batch = swz >> 4;
    int qblk  = swz & 15;

    const int tid = threadIdx.x;
    const int lane = tid & 63, w = tid >> 6;
    const int lo = lane & 15, hi = lane >> 4;

    const f16* Qb = Qp + (long)batch * WH * DIM + (long)qblk * 64 * DIM;
    const f16* Kb = Kp + (long)batch * LSEQ * DIM;

    f32x4 acc[32] = {};

    const int sr = tid >> 2;
    const int sk = (tid & 3) * 8;

    for (int k0 = 0; k0 < DIM; k0 += 32) {
        __syncthreads();
        #pragma unroll
        for (int it = 0; it < 8; ++it) {
            int row = sr + it * 64;
            *(f16x8*)&Ks[row][sk] = *(const f16x8*)(Kb + (long)row * DIM + k0 + sk);
        }
        *(f16x8*)&Qs[sr][sk] = *(const f16x8*)(Qb + (long)sr * DIM + k0 + sk);
        __syncthreads();

        f16x8 qf = *(const f16x8*)&Qs[w*16 + lo][hi*8];
        #pragma unroll
        for (int lt = 0; lt < 32; ++lt) {
            f16x8 kf = *(const f16x8*)&Ks[lt*16 + lo][hi*8];
            acc[lt] = __builtin_amdgcn_mfma_f32_16x16x32_f16(kf, qf, acc[lt], 0, 0, 0);
        }
    }

    // row softmax: 128 in-lane values + cross-hi-group reduce (lanes n, n+16, n+32, n+48)
    float mx = -1e30f;
    #pragma unroll
    for (int lt = 0; lt < 32; ++lt)
        #pragma unroll
        for (int r = 0; r < 4; ++r) mx = fmaxf(mx, acc[lt][r]);
    mx = fmaxf(mx, __shfl_xor(mx, 16));
    mx = fmaxf(mx, __shfl_xor(mx, 32));

    float sum = 0.f;
    #pragma unroll
    for (int lt = 0; lt < 32; ++lt) {
        #pragma unroll
        for (int r = 0; r < 4; ++r) {
            float p = exp2f((acc[lt][r] - mx) * 1.44269504088896f);
            acc[lt][r] = p;
            sum += p;
        }
    }
    sum += __shfl_xor(sum, 16);
    sum += __shfl_xor(sum, 32);
    float inv = 1.0f / sum;

    f16* Prow = P + (long)batch * WH * LSEQ + (long)(qblk*64 + w*16 + lo) * LSEQ;
    #pragma unroll
    for (int lt = 0; lt < 32; ++lt) {
        f16x4 o;
        #pragma unroll
        for (int r = 0; r < 4; ++r) o[r] = (f16)(acc[lt][r] * inv);
        *(f16x4*)(Prow + lt*16 + hi*4) = o;
    }
}

extern "C" void kernel_launch(void* const* d_in, const int* in_sizes, int n_in,
                              void* d_out, int out_size, void* d_ws, size_t ws_size,
                              hipStream_t stream) {
    const float* q   = (const float*)d_in[0];
    const float* k   = (const float*)d_in[1];
    const float* v   = (const float*)d_in[2];
    const float* q_w = (const float*)d_in[3];
    const float* q_b = (const float*)d_in[4];
    const float* k_w = (const float*)d_in[5];
    const float* k_b = (const float*)d_in[6];
    const float* v_w = (const float*)d_in[7];
    const float* v_b = (const float*)d_in[8];
    float* out = (float*)d_out;

    // workspace layout (f16 elements)
    const long NW   = 768L * 768;           // 589824 per weight
    const long NQP  = (long)NBATCH * WH * DIM;    // 25165824
    const long NKP  = (long)NBATCH * LSEQ * DIM;  // 12582912
    const long NP   = (long)NBATCH * WH * LSEQ;   // 16777216
    f16* qw16 = (f16*)d_ws;
    f16* kw16 = qw16 + NW;
    f16* vw16 = kw16 + NW;
    f16* Qp   = vw16 + NW;
    f16* Kp   = Qp + NQP;
    f16* VpT  = Kp + NKP;
    f16* P    = VpT + NKP;
    // total = 3*NW + NQP + 2*NKP + NP = 68,878,336 f16 = ~137.8 MB

    cast_f32_f16<<<NW/4/256, 256, 0, stream>>>(q_w, qw16, (int)NW);
    cast_f32_f16<<<NW/4/256, 256, 0, stream>>>(k_w, kw16, (int)NW);
    cast_f32_f16<<<NW/4/256, 256, 0, stream>>>(v_w, vw16, (int)NW);

    const float qscale = 0.03608439182435161f;  // 1/sqrt(768), folded into Qp (incl. bias)

    // Qp = (q * q_w^T + q_b) * scale      [32,1024,768] f16
    gemm_k<true,  false, true,  true><<<dim3(8, 6, 32), 256, 0, stream>>>(
        q, qw16, q_b, qscale, Qp, WH, DIM, DIM, (long)WH*DIM, 0, (long)WH*DIM);
    // Kp = k * k_w^T + k_b                [32,512,768] f16
    gemm_k<true,  false, true,  true><<<dim3(4, 6, 32), 256, 0, stream>>>(
        k, kw16, k_b, 1.0f, Kp, LSEQ, DIM, DIM, (long)LSEQ*DIM, 0, (long)LSEQ*DIM);
    // VpT = (v * v_w^T + v_b)^T           [32,768,512] f16
    gemm_k<true,  true,  true,  true><<<dim3(4, 6, 32), 256, 0, stream>>>(
        v, vw16, v_b, 1.0f, VpT, LSEQ, DIM, DIM, (long)LSEQ*DIM, 0, (long)DIM*LSEQ);
    // P = softmax(Qp * Kp^T)              [32,1024,512] f16
    attn_s<<<512, 256, 0, stream>>>(Qp, Kp, P);
    // out = P * Vp  (= P * VpT^T)         [32,1024,768] f32
    gemm_k<false, false, false, false><<<dim3(8, 6, 32), 256, 0, stream>>>(
        P, VpT, nullptr, 1.0f, out, WH, DIM, LSEQ, (long)WH*LSEQ, (long)DIM*LSEQ, (long)WH*DIM);
}

// Round 2
// 492.538 us; speedup vs baseline: 1.0553x; 1.0553x over previous
//
#include <hip/hip_runtime.h>
#include <hip/hip_bf16.h>

typedef _Float16 f16;
typedef _Float16 f16x8 __attribute__((ext_vector_type(8)));
typedef _Float16 f16x4 __attribute__((ext_vector_type(4)));
typedef float f32x4 __attribute__((ext_vector_type(4)));

#define NBATCH 32
#define WH     1024
#define LSEQ   512
#define DIM    768
#define BK     32

// async global->LDS, 16B per lane; dest = wave-uniform base + lane*16
#define GLD16(gp, lp) __builtin_amdgcn_global_load_lds( \
    (const __attribute__((address_space(1))) void*)(gp), \
    (__attribute__((address_space(3))) void*)(lp), 16, 0, 0)

// ---------------- cast fp32 -> fp16 (weights) ----------------
__global__ void cast_f32_f16(const float* __restrict__ src, f16* __restrict__ dst, int n) {
    int i = (blockIdx.x * blockDim.x + threadIdx.x) * 4;
    if (i < n) {
        float4 v = *(const float4*)(src + i);
        f16x4 o = { (f16)v.x, (f16)v.y, (f16)v.z, (f16)v.w };
        *(f16x4*)(dst + i) = o;
    }
}

// ---------------- batched K-major GEMM, dbuf + gld_lds + swizzle ----------------
// C[M,N] = (A[M,K] * B[N,K]^T + bias) * scale   (per batch; B shared if sB==0)
// A_MODE 0: A fp32, reg-staged + cvt + swizzled ds_write
// A_MODE 1: A fp16, gld_lds with pre-swizzled source
// LDS tile layout: [128][32] f16, 16B slot s of row r holds global slot (s ^ ((r>>1)&3)).
template<int A_MODE, bool TRANS_OUT, bool OUT_F16, bool HAS_BIAS>
__global__ __launch_bounds__(256, 2) void gemm_k(
    const void* __restrict__ Ap, const f16* __restrict__ Bp,
    const float* __restrict__ bias, float scale,
    void* __restrict__ Cp,
    int M, int N, int K,
    long sA, long sB, long sC)
{
    __shared__ __align__(16) f16 As[2][128][32];
    __shared__ __align__(16) f16 Bs[2][128][32];

    const int b  = blockIdx.z;
    const int m0 = blockIdx.x * 128;
    const int n0 = blockIdx.y * 128;
    const int tid  = threadIdx.x;
    const int lane = tid & 63;
    const int w    = tid >> 6;
    const int lo = lane & 15, hi = lane >> 4;
    const int wr = (w >> 1) * 64, wc = (w & 1) * 64;
    const int cr = lane >> 2;   // row within 16-row gld chunk
    const int cs = lane & 3;    // 16B slot within row

    const float* Af = (const float*)Ap + (long)b * sA;
    const f16*   Ah = (const f16*)Ap + (long)b * sA;
    const f16*   Bh = Bp + (long)b * sB;

    const int NT = K / BK;
    f32x4 acc[4][4] = {};

    // A_MODE 0 staging regs: 16 fp32 per thread (row ra, 16-col half)
    float4 ar0, ar1, ar2, ar3;
    const int ra = tid >> 1;
    const int s0 = (tid & 1) * 2;

    auto gldB = [&](int t, int buf) {
        int k0 = t * BK;
        #pragma unroll
        for (int i = 0; i < 2; ++i) {
            int ch = w * 2 + i;
            int r  = ch * 16 + cr;
            const f16* gp = Bh + (long)(n0 + r) * K + k0 + ((cs ^ ((r >> 1) & 3)) << 3);
            GLD16(gp, &Bs[buf][ch * 16][0]);
        }
    };
    auto gldA = [&](int t, int buf) {
        int k0 = t * BK;
        #pragma unroll
        for (int i = 0; i < 2; ++i) {
            int ch = w * 2 + i;
            int r  = ch * 16 + cr;
            const f16* gp = Ah + (long)(m0 + r) * K + k0 + ((cs ^ ((r >> 1) & 3)) << 3);
            GLD16(gp, &As[buf][ch * 16][0]);
        }
    };
    auto loadA = [&](int t) {
        const float* p = Af + (long)(m0 + ra) * K + t * BK + (tid & 1) * 16;
        ar0 = *(const float4*)p;
        ar1 = *(const float4*)(p + 4);
        ar2 = *(const float4*)(p + 8);
        ar3 = *(const float4*)(p + 12);
    };
    auto writeA = [&](int buf) {
        f16x8 h0 = { (f16)ar0.x,(f16)ar0.y,(f16)ar0.z,(f16)ar0.w,
                     (f16)ar1.x,(f16)ar1.y,(f16)ar1.z,(f16)ar1.w };
        f16x8 h1 = { (f16)ar2.x,(f16)ar2.y,(f16)ar2.z,(f16)ar2.w,
                     (f16)ar3.x,(f16)ar3.y,(f16)ar3.z,(f16)ar3.w };
        int f = (ra >> 1) & 3;
        *(f16x8*)&As[buf][ra][(s0 ^ f) << 3]       = h0;
        *(f16x8*)&As[buf][ra][((s0 + 1) ^ f) << 3] = h1;
    };
    auto compute = [&](int buf) {
        f16x8 af[4], bf[4];
        #pragma unroll
        for (int t2 = 0; t2 < 4; ++t2) {
            int rA = wr + t2 * 16 + lo;
            af[t2] = *(const f16x8*)&As[buf][rA][(hi ^ ((rA >> 1) & 3)) << 3];
            int rB = wc + t2 * 16 + lo;
            bf[t2] = *(const f16x8*)&Bs[buf][rB][(hi ^ ((rB >> 1) & 3)) << 3];
        }
        #pragma unroll
        for (int mt = 0; mt < 4; ++mt)
            #pragma unroll
            for (int nt = 0; nt < 4; ++nt)
                acc[mt][nt] = __builtin_amdgcn_mfma_f32_16x16x32_f16(af[mt], bf[nt], acc[mt][nt], 0, 0, 0);
    };

    // prologue: stage tile 0; prefetch A(1) to regs
    if constexpr (A_MODE == 0) { loadA(0); writeA(0); gldB(0, 0); loadA(1); }
    else                       { gldA(0, 0); gldB(0, 0); }

    int c = 0;
    for (int t = 0; t < NT; ++t) {
        __syncthreads();   // tile t fully staged (barrier drains vmcnt+lgkmcnt)
        if (t + 1 < NT) {
            gldB(t + 1, c ^ 1);
            if constexpr (A_MODE == 0) writeA(c ^ 1);
            else                       gldA(t + 1, c ^ 1);
        }
        if constexpr (A_MODE == 0) { if (t + 2 < NT) loadA(t + 2); }
        compute(c);
        c ^= 1;
    }

    #pragma unroll
    for (int nt = 0; nt < 4; ++nt) {
        int n = n0 + wc + nt * 16 + lo;
        float bv = HAS_BIAS ? bias[n] : 0.0f;
        #pragma unroll
        for (int mt = 0; mt < 4; ++mt) {
            int mbase = m0 + wr + mt * 16 + hi * 4;
            if constexpr (TRANS_OUT) {
                f16x4 o;
                #pragma unroll
                for (int r = 0; r < 4; ++r) o[r] = (f16)((acc[mt][nt][r] + bv) * scale);
                *(f16x4*)((f16*)Cp + (long)b * sC + (long)n * M + mbase) = o;
            } else if constexpr (OUT_F16) {
                #pragma unroll
                for (int r = 0; r < 4; ++r)
                    ((f16*)Cp)[(long)b * sC + (long)(mbase + r) * N + n] = (f16)((acc[mt][nt][r] + bv) * scale);
            } else {
                #pragma unroll
                for (int r = 0; r < 4; ++r)
                    ((float*)Cp)[(long)b * sC + (long)(mbase + r) * N + n] = (acc[mt][nt][r] + bv) * scale;
            }
        }
    }
}

// ---------------- S = Qp*Kp^T, softmax, P fp16 ----------------
// Block = 64 q-rows; swapped mfma(K,Q): lane holds S[l][q=lo] slice -> in-lane softmax.
// Ks/Qs double-buffered, gld_lds staged with pre-swizzled source, 1 barrier/K-step.
__global__ __launch_bounds__(256, 2) void attn_s(
    const f16* __restrict__ Qp, const f16* __restrict__ Kp, f16* __restrict__ P)
{
    __shared__ __align__(16) f16 Ks[2][512][32];
    __shared__ __align__(16) f16 Qs[2][64][32];

    int bid = blockIdx.x;
    int swz = (bid & 7) * 64 + (bid >> 3);   // 512 blocks, bijective XCD chunking
    int batch = swz >> 4;
    int qblk  = swz & 15;

    const int tid = threadIdx.x;
    const int lane = tid & 63, w = tid >> 6;
    const int lo = lane & 15, hi = lane >> 4;
    const int cr = lane >> 2, cs = lane & 3;

    const f16* Qb = Qp + (long)batch * WH * DIM + (long)qblk * 64 * DIM;
    const f16* Kb = Kp + (long)batch * LSEQ * DIM;

    f32x4 acc[32] = {};

    auto stage = [&](int t, int buf) {
        int k0 = t * BK;
        #pragma unroll
        for (int i = 0; i < 8; ++i) {
            int ch = w * 8 + i;
            int r  = ch * 16 + cr;
            const f16* gp = Kb + (long)r * DIM + k0 + ((cs ^ ((r >> 1) & 3)) << 3);
            GLD16(gp, &Ks[buf][ch * 16][0]);
        }
        {
            int r = w * 16 + cr;
            const f16* gp = Qb + (long)r * DIM + k0 + ((cs ^ ((r >> 1) & 3)) << 3);
            GLD16(gp, &Qs[buf][w * 16][0]);
        }
    };

    stage(0, 0);
    int c = 0;
    const int NT = DIM / BK;  // 24
    for (int t = 0; t < NT; ++t) {
        __syncthreads();
        if (t + 1 < NT) stage(t + 1, c ^ 1);
        int rQ = w * 16 + lo;
        f16x8 qf = *(const f16x8*)&Qs[c][rQ][(hi ^ ((rQ >> 1) & 3)) << 3];
        #pragma unroll
        for (int lt = 0; lt < 32; ++lt) {
            int rK = lt * 16 + lo;
            f16x8 kf = *(const f16x8*)&Ks[c][rK][(hi ^ ((rK >> 1) & 3)) << 3];
            acc[lt] = __builtin_amdgcn_mfma_f32_16x16x32_f16(kf, qf, acc[lt], 0, 0, 0);
        }
        c ^= 1;
    }

    float mx = -1e30f;
    #pragma unroll
    for (int lt = 0; lt < 32; ++lt)
        #pragma unroll
        for (int r = 0; r < 4; ++r) mx = fmaxf(mx, acc[lt][r]);
    mx = fmaxf(mx, __shfl_xor(mx, 16));
    mx = fmaxf(mx, __shfl_xor(mx, 32));

    float sum = 0.f;
    #pragma unroll
    for (int lt = 0; lt < 32; ++lt) {
        #pragma unroll
        for (int r = 0; r < 4; ++r) {
            float p = exp2f((acc[lt][r] - mx) * 1.44269504088896f);
            acc[lt][r] = p;
            sum += p;
        }
    }
    sum += __shfl_xor(sum, 16);
    sum += __shfl_xor(sum, 32);
    float inv = 1.0f / sum;

    f16* Prow = P + (long)batch * WH * LSEQ + (long)(qblk * 64 + w * 16 + lo) * LSEQ;
    #pragma unroll
    for (int lt = 0; lt < 32; ++lt) {
        f16x4 o;
        #pragma unroll
        for (int r = 0; r < 4; ++r) o[r] = (f16)(acc[lt][r] * inv);
        *(f16x4*)(Prow + lt * 16 + hi * 4) = o;
    }
}

extern "C" void kernel_launch(void* const* d_in, const int* in_sizes, int n_in,
                              void* d_out, int out_size, void* d_ws, size_t ws_size,
                              hipStream_t stream) {
    const float* q   = (const float*)d_in[0];
    const float* k   = (const float*)d_in[1];
    const float* v   = (const float*)d_in[2];
    const float* q_w = (const float*)d_in[3];
    const float* q_b = (const float*)d_in[4];
    const float* k_w = (const float*)d_in[5];
    const float* k_b = (const float*)d_in[6];
    const float* v_w = (const float*)d_in[7];
    const float* v_b = (const float*)d_in[8];
    float* out = (float*)d_out;

    const long NW   = 768L * 768;
    const long NQP  = (long)NBATCH * WH * DIM;
    const long NKP  = (long)NBATCH * LSEQ * DIM;
    f16* qw16 = (f16*)d_ws;
    f16* kw16 = qw16 + NW;
    f16* vw16 = kw16 + NW;
    f16* Qp   = vw16 + NW;
    f16* Kp   = Qp + NQP;
    f16* VpT  = Kp + NKP;
    f16* P    = VpT + NKP;

    cast_f32_f16<<<NW/4/256, 256, 0, stream>>>(q_w, qw16, (int)NW);
    cast_f32_f16<<<NW/4/256, 256, 0, stream>>>(k_w, kw16, (int)NW);
    cast_f32_f16<<<NW/4/256, 256, 0, stream>>>(v_w, vw16, (int)NW);

    const float qscale = 0.03608439182435161f;  // 1/sqrt(768)

    // Qp = (q * q_w^T + q_b) * scale      [32,1024,768] f16
    gemm_k<0, false, true,  true><<<dim3(8, 6, 32), 256, 0, stream>>>(
        q, qw16, q_b, qscale, Qp, WH, DIM, DIM, (long)WH*DIM, 0, (long)WH*DIM);
    // Kp = k * k_w^T + k_b                [32,512,768] f16
    gemm_k<0, false, true,  true><<<dim3(4, 6, 32), 256, 0, stream>>>(
        k, kw16, k_b, 1.0f, Kp, LSEQ, DIM, DIM, (long)LSEQ*DIM, 0, (long)LSEQ*DIM);
    // VpT = (v * v_w^T + v_b)^T           [32,768,512] f16
    gemm_k<0, true,  true,  true><<<dim3(4, 6, 32), 256, 0, stream>>>(
        v, vw16, v_b, 1.0f, VpT, LSEQ, DIM, DIM, (long)LSEQ*DIM, 0, (long)DIM*LSEQ);
    // P = softmax(Qp * Kp^T)              [32,1024,512] f16
    attn_s<<<512, 256, 0, stream>>>(Qp, Kp, P);
    // out = P * Vp                        [32,1024,768] f32
    gemm_k<1, false, false, false><<<dim3(8, 6, 32), 256, 0, stream>>>(
        P, VpT, nullptr, 1.0f, out, WH, DIM, LSEQ, (long)WH*LSEQ, (long)DIM*LSEQ, (long)WH*DIM);
}